// Round 1
// baseline (597.309 us; speedup 1.0000x reference)
//
#include <hip/hip_runtime.h>
#include <hip/hip_bf16.h>

#define BB   8
#define TT   12
#define NN   512
#define HH   64
#define PP   12
#define MM   (BB*TT)          // 96
#define NEGV (-9e15f)
#define ROWS 16               // rows per gat block (4 per wave)

// ---------------------------------------------------------------- prep
__global__ void prep_kernel(const float* __restrict__ W_ih, const float* __restrict__ W_hh,
                            float* __restrict__ WihT, float* __restrict__ WhhT) {
    int tid = threadIdx.x;
    for (int i = tid; i < 66 * 192; i += 256) {
        int c = i / 192, k = i % 192;
        WihT[i] = W_ih[k * 66 + c];
    }
    for (int i = tid; i < 64 * 192; i += 256) {
        int c = i / 192, k = i % 192;
        WhhT[i] = W_hh[k * 64 + c];
    }
}

// ---------------------------------------------------------------- Wh = x @ W  (per gat)
__global__ __launch_bounds__(256) void wh_kernel(const float* __restrict__ X,
                                                 const float* __restrict__ Wg,
                                                 const float* __restrict__ Wn,
                                                 const float* __restrict__ Wd,
                                                 float* __restrict__ Wh) {
    int idx = blockIdx.x * 256 + threadIdx.x;       // 3*96*512*64 total, exact grid
    int g = idx / (MM * NN * HH);
    int r = idx % (MM * NN * HH);
    int m = r >> 15;             // /(512*64)
    int n = (r >> 6) & 511;
    int h = r & 63;
    const float* W = (g == 0) ? Wg : (g == 1 ? Wn : Wd);
    float x0 = X[(m * NN + n) * 2 + 0];
    float x1 = X[(m * NN + n) * 2 + 1];
    Wh[idx] = x0 * W[h] + x1 * W[64 + h];
}

// ---------------------------------------------------------------- fused GAT (softmax + att@Wh + elu)
__global__ __launch_bounds__(256) void gat_kernel(
    const float* __restrict__ X,
    const int* __restrict__ Gs, const int* __restrict__ Gn, const int* __restrict__ Gd,
    const float* __restrict__ Wg, const float* __restrict__ a1g, const float* __restrict__ a2g,
    const float* __restrict__ Wn_, const float* __restrict__ a1n, const float* __restrict__ a2n,
    const float* __restrict__ Wd_, const float* __restrict__ a1d, const float* __restrict__ a2d,
    const float* __restrict__ Wh, float* __restrict__ gatout)
{
    __shared__ float s2_lds[NN];
    __shared__ __align__(16) float p_lds[ROWS * NN];   // 32 KB

    int bid  = blockIdx.x;
    int g    = bid / (MM * (NN / ROWS));
    int rem  = bid % (MM * (NN / ROWS));
    int m    = rem / (NN / ROWS);
    int tile = rem % (NN / ROWS);

    const int*   adj = (g == 0) ? Gs : (g == 1 ? Gn : Gd);
    const float* Wp  = (g == 0) ? Wg : (g == 1 ? Wn_ : Wd_);
    const float* a1  = (g == 0) ? a1g : (g == 1 ? a1n : a1d);
    const float* a2  = (g == 0) ? a2g : (g == 1 ? a2n : a2d);

    int tid = threadIdx.x;
    int lane = tid & 63;
    int w = tid >> 6;

    // 4 scalars: (W@a1)[0..1], (W@a2)[0..1]  — redundant per wave, butterfly reduce
    float w0 = Wp[lane], w1 = Wp[64 + lane];
    float va1 = a1[lane], va2 = a2[lane];
    float r0 = w0 * va1, r1 = w1 * va1, r2 = w0 * va2, r3 = w1 * va2;
    #pragma unroll
    for (int off = 32; off; off >>= 1) {
        r0 += __shfl_xor(r0, off);
        r1 += __shfl_xor(r1, off);
        r2 += __shfl_xor(r2, off);
        r3 += __shfl_xor(r3, off);
    }

    // stage s2[j] = x0_j*(W@a2)[0] + x1_j*(W@a2)[1]
    const float* Xm = X + m * NN * 2;
    for (int j = tid; j < NN; j += 256) {
        float2 x = *(const float2*)(Xm + j * 2);
        s2_lds[j] = x.x * r2 + x.y * r3;
    }
    __syncthreads();

    const float* Whp = Wh + (size_t)(g * MM + m) * NN * HH;
    int r_base = w * 4;                 // 4 rows per wave, 16 per block

    // ---- phase A: masked softmax rows -> p_lds (unnormalized), rsum in regs
    float rsum[4];
    #pragma unroll
    for (int rr = 0; rr < 4; ++rr) {
        int rl = r_base + rr;
        int i  = tile * ROWS + rl;
        float2 xi = *(const float2*)(Xm + i * 2);
        float s1 = xi.x * r0 + xi.y * r1;
        const int* arow = adj + i * NN;
        float e[8];
        float mx = NEGV;
        #pragma unroll
        for (int jj = 0; jj < 8; ++jj) {
            int j = jj * 64 + lane;
            float t = s1 + s2_lds[j];
            t = fmaxf(t, 0.2f * t);                 // leaky_relu(0.2)
            e[jj] = (arow[j] > 0) ? t : NEGV;
            mx = fmaxf(mx, e[jj]);
        }
        #pragma unroll
        for (int off = 32; off; off >>= 1) mx = fmaxf(mx, __shfl_xor(mx, off));
        float s = 0.f;
        #pragma unroll
        for (int jj = 0; jj < 8; ++jj) {
            float p = __expf(e[jj] - mx);
            p_lds[rl * NN + jj * 64 + lane] = p;
            s += p;
        }
        #pragma unroll
        for (int off = 32; off; off >>= 1) s += __shfl_xor(s, off);
        rsum[rr] = 1.0f / s;
    }
    __syncthreads();

    // ---- phase B: out[i,h] = elu( (1/sum_i) * sum_j p[i,j]*Wh[j,h] )
    float acc[4] = {0.f, 0.f, 0.f, 0.f};
    for (int j0 = 0; j0 < NN; j0 += 4) {
        float wh0 = Whp[(j0 + 0) * HH + lane];
        float wh1 = Whp[(j0 + 1) * HH + lane];
        float wh2 = Whp[(j0 + 2) * HH + lane];
        float wh3 = Whp[(j0 + 3) * HH + lane];
        #pragma unroll
        for (int rr = 0; rr < 4; ++rr) {
            float4 p = *(const float4*)&p_lds[(r_base + rr) * NN + j0];
            acc[rr] += p.x * wh0 + p.y * wh1 + p.z * wh2 + p.w * wh3;
        }
    }
    #pragma unroll
    for (int rr = 0; rr < 4; ++rr) {
        int i = tile * ROWS + r_base + rr;
        float v = acc[rr] * rsum[rr];
        v = (v > 0.f) ? v : expm1f(v);              // elu
        gatout[((size_t)(g * MM + m) * NN + i) * HH + lane] = v;
    }
}

// ---------------------------------------------------------------- spatial fuse + GRU input transform
__global__ __launch_bounds__(256) void fuse_kernel(
    const float* __restrict__ X, const float* __restrict__ gatout,
    const float* __restrict__ Wf, const float* __restrict__ bf,
    const float* __restrict__ WihT, const float* __restrict__ b_ih,
    float* __restrict__ gx)
{
    __shared__ __align__(16) float cat_lds[4][128];
    __shared__ __align__(16) float gi_lds[4][68];
    int tid = threadIdx.x, lane = tid & 63, w = tid >> 6;
    int node = blockIdx.x * 4 + w;                  // < 49152 exact
    int mm = node >> 9, n = node & 511;
    int b = mm / TT, t = mm % TT;
    int row = b * NN + n;

    float fs  = gatout[(size_t)node * HH + lane];
    float fnd = gatout[(size_t)(49152 + node) * HH + lane]
              + gatout[(size_t)(2 * 49152 + node) * HH + lane];
    cat_lds[w][lane] = fs;
    cat_lds[w][64 + lane] = fnd;
    __syncthreads();

    float sp = bf[lane];
    for (int c = 0; c < 128; c += 4) {
        float4 cc = *(const float4*)&cat_lds[w][c];
        sp += cc.x * Wf[(c + 0) * HH + lane]
            + cc.y * Wf[(c + 1) * HH + lane]
            + cc.z * Wf[(c + 2) * HH + lane]
            + cc.w * Wf[(c + 3) * HH + lane];
    }
    sp = fmaxf(sp, 0.f);
    gi_lds[w][lane] = sp;
    if (lane < 2) gi_lds[w][64 + lane] = X[(mm * NN + n) * 2 + lane];
    __syncthreads();

    float acc0 = b_ih[lane], acc1 = b_ih[64 + lane], acc2 = b_ih[128 + lane];
    for (int c = 0; c < 66; c += 2) {
        float2 cc = *(const float2*)&gi_lds[w][c];
        acc0 += cc.x * WihT[c * 192 + lane]       + cc.y * WihT[(c + 1) * 192 + lane];
        acc1 += cc.x * WihT[c * 192 + 64 + lane]  + cc.y * WihT[(c + 1) * 192 + 64 + lane];
        acc2 += cc.x * WihT[c * 192 + 128 + lane] + cc.y * WihT[(c + 1) * 192 + 128 + lane];
    }
    size_t o = ((size_t)row * TT + t) * 192;
    gx[o + lane]       = acc0;
    gx[o + 64 + lane]  = acc1;
    gx[o + 128 + lane] = acc2;
}

// ---------------------------------------------------------------- GRU scan + MLP head
__global__ __launch_bounds__(256) void gru_head_kernel(
    const float* __restrict__ gx, const float* __restrict__ WhhT,
    const float* __restrict__ b_hh,
    const float* __restrict__ W1, const float* __restrict__ b1,
    const float* __restrict__ W2, const float* __restrict__ b2,
    float* __restrict__ out)
{
    __shared__ float whh[64 * 192];                 // 48 KB
    __shared__ float hbuf[4][64];
    __shared__ float z1buf[4][32];
    int tid = threadIdx.x, lane = tid & 63, w = tid >> 6;
    int row = blockIdx.x * 4 + w;                   // < 4096 exact

    for (int i = tid; i < 64 * 192; i += 256) whh[i] = WhhT[i];
    __syncthreads();

    float bhr = b_hh[lane], bhz = b_hh[64 + lane], bhn = b_hh[128 + lane];
    float h = 0.f;
    for (int t = 0; t < TT; ++t) {
        size_t o = ((size_t)row * TT + t) * 192;
        float gxr = gx[o + lane], gxz = gx[o + 64 + lane], gxn = gx[o + 128 + lane];
        float ghr = bhr, ghz = bhz, ghn = bhn;
        for (int j = 0; j < 64; ++j) {
            float hj = __shfl(h, j);
            ghr += hj * whh[j * 192 + lane];
            ghz += hj * whh[j * 192 + 64 + lane];
            ghn += hj * whh[j * 192 + 128 + lane];
        }
        float r  = 1.f / (1.f + __expf(-(gxr + ghr)));
        float z  = 1.f / (1.f + __expf(-(gxz + ghz)));
        float nn = tanhf(gxn + r * ghn);
        h = (1.f - z) * nn + z * h;
    }

    hbuf[w][lane] = h;
    __syncthreads();
    if (lane < 32) {
        float z1 = b1[lane];
        for (int j = 0; j < 64; ++j) z1 += hbuf[w][j] * W1[j * 32 + lane];
        z1buf[w][lane] = fmaxf(z1, 0.f);
    }
    __syncthreads();
    if (lane < PP) {
        float o = b2[lane];
        for (int c = 0; c < 32; ++c) o += z1buf[w][c] * W2[c * PP + lane];
        int bb = row >> 9, n = row & 511;
        out[bb * (PP * NN) + lane * NN + n] = o;
    }
}

// ---------------------------------------------------------------- launch
extern "C" void kernel_launch(void* const* d_in, const int* in_sizes, int n_in,
                              void* d_out, int out_size, void* d_ws, size_t ws_size,
                              hipStream_t stream) {
    const float* X    = (const float*)d_in[0];
    const int*   Gs   = (const int*)d_in[1];
    const int*   Gn   = (const int*)d_in[2];
    const int*   Gd   = (const int*)d_in[3];
    const float* Wg   = (const float*)d_in[4];
    const float* a1g  = (const float*)d_in[5];
    const float* a2g  = (const float*)d_in[6];
    const float* Wn   = (const float*)d_in[7];
    const float* a1n  = (const float*)d_in[8];
    const float* a2n  = (const float*)d_in[9];
    const float* Wd   = (const float*)d_in[10];
    const float* a1d  = (const float*)d_in[11];
    const float* a2d  = (const float*)d_in[12];
    const float* Wf   = (const float*)d_in[13];
    const float* bf   = (const float*)d_in[14];
    const float* W_ih = (const float*)d_in[15];
    const float* W_hh = (const float*)d_in[16];
    const float* b_ih = (const float*)d_in[17];
    const float* b_hh = (const float*)d_in[18];
    const float* W1   = (const float*)d_in[19];
    const float* b1   = (const float*)d_in[20];
    const float* W2   = (const float*)d_in[21];
    const float* b2   = (const float*)d_in[22];
    float* out = (float*)d_out;

    const size_t BIG = 37748736;                    // 3*96*512*64 floats (bytes)
    char* ws = (char*)d_ws;
    float* Wh     = (float*)ws;                     // [3][96][512][64]
    float* gatout = (float*)(ws + BIG);             // [3][96][512][64]
    float* gx     = (float*)ws;                     // aliases Wh (dead after gat_kernel)
    float* WihT   = (float*)(ws + 2 * BIG);         // [66][192]
    float* WhhT   = WihT + 66 * 192;                // [64][192]

    prep_kernel<<<1, 256, 0, stream>>>(W_ih, W_hh, WihT, WhhT);
    wh_kernel<<<(3 * MM * NN * HH) / 256, 256, 0, stream>>>(X, Wg, Wn, Wd, Wh);
    gat_kernel<<<3 * MM * (NN / ROWS), 256, 0, stream>>>(
        X, Gs, Gn, Gd, Wg, a1g, a2g, Wn, a1n, a2n, Wd, a1d, a2d, Wh, gatout);
    fuse_kernel<<<(MM * NN) / 4, 256, 0, stream>>>(X, gatout, Wf, bf, WihT, b_ih, gx);
    gru_head_kernel<<<(BB * NN) / 4, 256, 0, stream>>>(gx, WhhT, b_hh, W1, b1, W2, b2, out);
}

// Round 2
// 253.644 us; speedup vs baseline: 2.3549x; 2.3549x over previous
//
#include <hip/hip_runtime.h>
#include <hip/hip_bf16.h>

#define BB 8
#define TT 12
#define NN 512
#define HH 64
#define PP 12
#define MM 96
#define NEGV (-9e15f)

// ---------------------------------------------------------------- WihT = W_ih^T  [66][192]
__global__ void prep_w_kernel(const float* __restrict__ W_ih, float* __restrict__ WihT) {
    int i = blockIdx.x * 256 + threadIdx.x;
    if (i < 66 * 192) {
        int c = i / 192, k = i % 192;
        WihT[i] = W_ih[k * 66 + c];     // coalesced store, gathered load (one-time)
    }
}

// ---------------------------------------------------------------- pack adj -> bitmasks [3*512][16]u32
__global__ void pack_kernel(const int* __restrict__ Gs, const int* __restrict__ Gn,
                            const int* __restrict__ Gd, unsigned* __restrict__ maskws) {
    int tid = threadIdx.x, lane = tid & 63, w = tid >> 6;
    int gr = blockIdx.x * 4 + w;                    // 0..1535
    int g = gr >> 9, r = gr & 511;
    const int* adj = (g == 0) ? Gs : (g == 1 ? Gn : Gd);
    for (int jw = 0; jw < 8; ++jw) {
        unsigned long long b = __ballot(adj[r * NN + jw * 64 + lane] > 0);
        if (lane == 0) {
            maskws[gr * 16 + jw * 2]     = (unsigned)b;
            maskws[gr * 16 + jw * 2 + 1] = (unsigned)(b >> 32);
        }
    }
}

// ---------------------------------------------------------------- GAT -> U[g][m][i][2]
// u = (sum_j p_ij * x_j) / (sum_j p_ij) ; out[i,h] = elu(u0*W[0,h]+u1*W[1,h]) done later.
#define PROC_WORD(word, jbase)                                        \
    _Pragma("unroll")                                                 \
    for (int j2 = 0; j2 < 32; ++j2) {                                 \
        float4 v = s2p[(jbase) + j2];                                 \
        float tv = s1 + v.x;                                          \
        tv = fmaxf(tv, 0.2f * tv);                                    \
        float e = ((word >> j2) & 1u) ? tv : NEGV;                    \
        float p = __expf(e);                                          \
        s += p;                                                       \
        sx0 = fmaf(p, v.y, sx0);                                      \
        sx1 = fmaf(p, v.z, sx1);                                      \
    }

__global__ __launch_bounds__(256) void gat_s_kernel(
    const float* __restrict__ X,
    const float* __restrict__ Wg, const float* __restrict__ a1g, const float* __restrict__ a2g,
    const float* __restrict__ Wn_, const float* __restrict__ a1n, const float* __restrict__ a2n,
    const float* __restrict__ Wd_, const float* __restrict__ a1d, const float* __restrict__ a2d,
    const unsigned* __restrict__ maskws, float* __restrict__ U)
{
    __shared__ __align__(16) float4 s2x[4][NN];     // per-wave private slice, 32 KB
    int tid = threadIdx.x, lane = tid & 63, w = tid >> 6;
    int wid = blockIdx.x * 4 + w;                   // 0..2303 = g(3) * m(96) * rg(8)
    int g = wid / 768;
    int rem = wid % 768;
    int m = rem / 8;
    int rg = rem % 8;

    const float* Wp = (g == 0) ? Wg : (g == 1 ? Wn_ : Wd_);
    const float* a1 = (g == 0) ? a1g : (g == 1 ? a1n : a1d);
    const float* a2 = (g == 0) ? a2g : (g == 1 ? a2n : a2d);

    // r0,r1 = (W@a1)[0..1];  r2,r3 = (W@a2)[0..1]   (wave butterfly reduce)
    float w0 = Wp[lane], w1 = Wp[HH + lane];
    float va1 = a1[lane], va2 = a2[lane];
    float r0 = w0 * va1, r1 = w1 * va1, r2 = w0 * va2, r3 = w1 * va2;
    #pragma unroll
    for (int off = 32; off; off >>= 1) {
        r0 += __shfl_xor(r0, off); r1 += __shfl_xor(r1, off);
        r2 += __shfl_xor(r2, off); r3 += __shfl_xor(r3, off);
    }

    // stage (s2_j, x0_j, x1_j) for this m
    const float* Xm = X + m * (NN * 2);
    #pragma unroll
    for (int q = 0; q < 8; ++q) {
        int j = q * 64 + lane;
        float2 x = *(const float2*)(Xm + j * 2);
        s2x[w][j] = make_float4(x.x * r2 + x.y * r3, x.x, x.y, 0.f);
    }
    const float4* s2p = &s2x[w][0];

    int i = rg * 64 + lane;                         // my row
    float2 xi = *(const float2*)(Xm + i * 2);
    float s1 = xi.x * r0 + xi.y * r1;

    const uint4* mw4 = (const uint4*)(maskws + (g * NN + i) * 16);

    float s = 0.f, sx0 = 0.f, sx1 = 0.f;
    #pragma unroll 1
    for (int jw4 = 0; jw4 < 4; ++jw4) {
        uint4 mq = mw4[jw4];
        int jb = jw4 * 128;
        PROC_WORD(mq.x, jb)
        PROC_WORD(mq.y, jb + 32)
        PROC_WORD(mq.z, jb + 64)
        PROC_WORD(mq.w, jb + 96)
    }

    float inv = 1.0f / s;
    *(float2*)&U[((size_t)(g * MM + m) * NN + i) * 2] = make_float2(sx0 * inv, sx1 * inv);
}

// ---------------------------------------------------------------- fuse: U -> cat -> spatial -> gx
__global__ __launch_bounds__(256) void fuse_kernel(
    const float* __restrict__ X, const float* __restrict__ U,
    const float* __restrict__ Wg, const float* __restrict__ Wn_, const float* __restrict__ Wd_,
    const float* __restrict__ Wf, const float* __restrict__ bf,
    const float* __restrict__ WihT, const float* __restrict__ b_ih,
    float* __restrict__ gx)
{
    __shared__ __align__(16) float cat[128][68];    // 34.8 KB
    __shared__ __align__(16) float sp[66][68];      // 18 KB  (rows 64,65 = x0,x1)
    int tid = threadIdx.x, lane = tid & 63, w = tid >> 6;
    int m = blockIdx.x >> 3, n0 = (blockIdx.x & 7) * 64;
    int b = m / TT, t = m % TT;

    // stage cat[c][n]: c<64 -> f_s, c>=64 -> f_nd (elu applied here; gatout never materialized)
    for (int idx = tid; idx < 128 * 64; idx += 256) {
        int c = idx >> 6, n = idx & 63;
        int node = m * NN + n0 + n;
        float v;
        if (c < 64) {
            float2 u = *(const float2*)&U[(size_t)node * 2];
            float z = u.x * Wg[c] + u.y * Wg[64 + c];
            v = z > 0.f ? z : expm1f(z);
        } else {
            int cc = c - 64;
            float2 un = *(const float2*)&U[(size_t)(49152 + node) * 2];
            float2 ud = *(const float2*)&U[(size_t)(2 * 49152 + node) * 2];
            float zn = un.x * Wn_[cc] + un.y * Wn_[64 + cc];
            float zd = ud.x * Wd_[cc] + ud.y * Wd_[64 + cc];
            v = (zn > 0.f ? zn : expm1f(zn)) + (zd > 0.f ? zd : expm1f(zd));
        }
        cat[c][n] = v;
    }
    // x rows into sp (each wave writes its own node columns -> no extra barrier later)
    if (lane < 32) {
        int nl = lane >> 1, cc = lane & 1;
        sp[64 + cc][w * 16 + nl] = X[((size_t)m * NN + n0 + w * 16 + nl) * 2 + cc];
    }
    __syncthreads();

    // GEMM1: spatial[h=lane][n = w*16+q] = relu(bf + sum_c cat[c][n]*Wf[c][h])
    float acc[16];
    float bfl = bf[lane];
    #pragma unroll
    for (int q = 0; q < 16; ++q) acc[q] = bfl;
    #pragma unroll 4
    for (int c = 0; c < 128; ++c) {
        float wf = Wf[c * 64 + lane];
        #pragma unroll
        for (int qq = 0; qq < 4; ++qq) {
            float4 cv = *(const float4*)&cat[c][w * 16 + qq * 4];
            acc[qq * 4 + 0] = fmaf(cv.x, wf, acc[qq * 4 + 0]);
            acc[qq * 4 + 1] = fmaf(cv.y, wf, acc[qq * 4 + 1]);
            acc[qq * 4 + 2] = fmaf(cv.z, wf, acc[qq * 4 + 2]);
            acc[qq * 4 + 3] = fmaf(cv.w, wf, acc[qq * 4 + 3]);
        }
    }
    #pragma unroll
    for (int q = 0; q < 16; ++q) sp[lane][w * 16 + q] = fmaxf(acc[q], 0.f);
    // no barrier: GEMM2 below reads only this wave's own sp columns (in-order LDS)

    // GEMM2: gx[k][n] = b_ih + sum_{c<66} sp[c][n]*WihT[c][k], k = lane+{0,64,128}
    float a0[16], a1v[16], a2v[16];
    float b0 = b_ih[lane], b1q = b_ih[64 + lane], b2q = b_ih[128 + lane];
    #pragma unroll
    for (int q = 0; q < 16; ++q) { a0[q] = b0; a1v[q] = b1q; a2v[q] = b2q; }
    #pragma unroll 2
    for (int c = 0; c < 66; ++c) {
        float wv0 = WihT[c * 192 + lane];
        float wv1 = WihT[c * 192 + 64 + lane];
        float wv2 = WihT[c * 192 + 128 + lane];
        #pragma unroll
        for (int qq = 0; qq < 4; ++qq) {
            float4 sv = *(const float4*)&sp[c][w * 16 + qq * 4];
            float sq[4] = {sv.x, sv.y, sv.z, sv.w};
            #pragma unroll
            for (int u = 0; u < 4; ++u) {
                a0[qq * 4 + u]  = fmaf(sq[u], wv0, a0[qq * 4 + u]);
                a1v[qq * 4 + u] = fmaf(sq[u], wv1, a1v[qq * 4 + u]);
                a2v[qq * 4 + u] = fmaf(sq[u], wv2, a2v[qq * 4 + u]);
            }
        }
    }
    #pragma unroll
    for (int q = 0; q < 16; ++q) {
        int n = n0 + w * 16 + q;
        size_t o = ((size_t)(b * NN + n) * TT + t) * 192;
        gx[o + lane]       = a0[q];
        gx[o + 64 + lane]  = a1v[q];
        gx[o + 128 + lane] = a2v[q];
    }
}

// ---------------------------------------------------------------- GRU scan + MLP head
__global__ __launch_bounds__(256) void gru_head_kernel(
    const float* __restrict__ gx, const float* __restrict__ W_hh,
    const float* __restrict__ b_hh,
    const float* __restrict__ W1, const float* __restrict__ b1,
    const float* __restrict__ W2, const float* __restrict__ b2,
    float* __restrict__ out)
{
    __shared__ __align__(16) float4 whh4[64 * 64];  // [j][l] -> (Wr,Wz,Wn,0)  64 KB
    __shared__ __align__(16) float hlds[4][64];
    __shared__ float z1buf[4][32];
    int tid = threadIdx.x, lane = tid & 63, w = tid >> 6;
    int row = blockIdx.x * 4 + w;                   // < 4096

    for (int idx = tid; idx < 4096; idx += 256) {
        int l = idx & 63, j = idx >> 6;
        whh4[idx] = make_float4(W_hh[l * 64 + j], W_hh[(64 + l) * 64 + j],
                                W_hh[(128 + l) * 64 + j], 0.f);
    }
    __syncthreads();

    float bhr = b_hh[lane], bhz = b_hh[64 + lane], bhn = b_hh[128 + lane];
    float h = 0.f;
    for (int t = 0; t < TT; ++t) {
        size_t o = ((size_t)row * TT + t) * 192;
        float gxr = gx[o + lane], gxz = gx[o + 64 + lane], gxn = gx[o + 128 + lane];
        hlds[w][lane] = h;                          // same-wave LDS ops are in-order
        float ghr = bhr, ghz = bhz, ghn = bhn;
        #pragma unroll 4
        for (int j = 0; j < 64; j += 4) {
            float4 hb = *(const float4*)&hlds[w][j];
            float4 q0 = whh4[(j + 0) * 64 + lane];
            float4 q1 = whh4[(j + 1) * 64 + lane];
            float4 q2 = whh4[(j + 2) * 64 + lane];
            float4 q3 = whh4[(j + 3) * 64 + lane];
            ghr = fmaf(hb.x, q0.x, fmaf(hb.y, q1.x, fmaf(hb.z, q2.x, fmaf(hb.w, q3.x, ghr))));
            ghz = fmaf(hb.x, q0.y, fmaf(hb.y, q1.y, fmaf(hb.z, q2.y, fmaf(hb.w, q3.y, ghz))));
            ghn = fmaf(hb.x, q0.z, fmaf(hb.y, q1.z, fmaf(hb.z, q2.z, fmaf(hb.w, q3.z, ghn))));
        }
        float r = 1.f / (1.f + __expf(-(gxr + ghr)));
        float z = 1.f / (1.f + __expf(-(gxz + ghz)));
        float nv = tanhf(gxn + r * ghn);
        h = (1.f - z) * nv + z * h;
    }

    hlds[w][lane] = h;
    if (lane < 32) {
        float z1 = b1[lane];
        #pragma unroll 8
        for (int j = 0; j < 64; ++j) z1 += hlds[w][j] * W1[j * 32 + lane];
        z1buf[w][lane] = fmaxf(z1, 0.f);
    }
    if (lane < PP) {
        float o = b2[lane];
        #pragma unroll 8
        for (int c = 0; c < 32; ++c) o += z1buf[w][c] * W2[c * PP + lane];
        int bb = row >> 9, n = row & 511;
        out[bb * (PP * NN) + lane * NN + n] = o;
    }
}

// ---------------------------------------------------------------- launch
extern "C" void kernel_launch(void* const* d_in, const int* in_sizes, int n_in,
                              void* d_out, int out_size, void* d_ws, size_t ws_size,
                              hipStream_t stream) {
    const float* X    = (const float*)d_in[0];
    const int*   Gs   = (const int*)d_in[1];
    const int*   Gn   = (const int*)d_in[2];
    const int*   Gd   = (const int*)d_in[3];
    const float* Wg   = (const float*)d_in[4];
    const float* a1g  = (const float*)d_in[5];
    const float* a2g  = (const float*)d_in[6];
    const float* Wn   = (const float*)d_in[7];
    const float* a1n  = (const float*)d_in[8];
    const float* a2n  = (const float*)d_in[9];
    const float* Wd   = (const float*)d_in[10];
    const float* a1d  = (const float*)d_in[11];
    const float* a2d  = (const float*)d_in[12];
    const float* Wf   = (const float*)d_in[13];
    const float* bf   = (const float*)d_in[14];
    const float* W_ih = (const float*)d_in[15];
    const float* W_hh = (const float*)d_in[16];
    const float* b_ih = (const float*)d_in[17];
    const float* b_hh = (const float*)d_in[18];
    const float* W1   = (const float*)d_in[19];
    const float* b1   = (const float*)d_in[20];
    const float* W2   = (const float*)d_in[21];
    const float* b2   = (const float*)d_in[22];
    float* out = (float*)d_out;

    float* gxw    = (float*)d_ws;                   // [4096][12][192] = 9,437,184 f
    float* U      = gxw + 9437184;                  // [3][96][512][2] = 294,912 f
    float* WihT   = U + 294912;                     // [66][192] = 12,672 f
    unsigned* maskws = (unsigned*)(WihT + 12672);   // [1536][16] u32

    prep_w_kernel<<<50, 256, 0, stream>>>(W_ih, WihT);
    pack_kernel<<<384, 256, 0, stream>>>(Gs, Gn, Gd, maskws);
    gat_s_kernel<<<576, 256, 0, stream>>>(X, Wg, a1g, a2g, Wn, a1n, a2n, Wd, a1d, a2d,
                                          maskws, U);
    fuse_kernel<<<768, 256, 0, stream>>>(X, U, Wg, Wn, Wd, Wf, bf, WihT, b_ih, gxw);
    gru_head_kernel<<<1024, 256, 0, stream>>>(gxw, W_hh, b_hh, W1, b1, W2, b2, out);
}

// Round 10
// 202.231 us; speedup vs baseline: 2.9536x; 1.2542x over previous
//
#include <hip/hip_runtime.h>
#include <hip/hip_bf16.h>

#define BB 8
#define TT 12
#define NN 512
#define HH 64
#define PP 12
#define MM 96

typedef _Float16 half2v __attribute__((ext_vector_type(2)));

__device__ __forceinline__ half2v as_h2(unsigned u){ union{unsigned u; half2v h;} c; c.u=u; return c.h; }
__device__ __forceinline__ unsigned h2_as_u(half2v h){ union{unsigned u; half2v h;} c; c.h=h; return c.u; }
__device__ __forceinline__ float rlane(float v, int l){
    return __int_as_float(__builtin_amdgcn_readlane(__float_as_int(v), l));
}

#if defined(__has_builtin)
#if __has_builtin(__builtin_amdgcn_fdot2)
#define HAVE_FDOT2 1
#endif
#endif
__device__ __forceinline__ float fdot2(half2v a, half2v b, float c){
#ifdef HAVE_FDOT2
    return __builtin_amdgcn_fdot2(a, b, c, false);
#else
    return c + (float)a.x*(float)b.x + (float)a.y*(float)b.y;
#endif
}

__device__ __forceinline__ unsigned pkf16(float a, float b){
    half2v h; h.x = (_Float16)a; h.y = (_Float16)b; return h2_as_u(h);
}

// ---------------------------------------------------------------- prep: WihT, f16-packed W_hh (SoA), rcoef
__global__ void prep_kernel(const float* __restrict__ W_ih, const float* __restrict__ W_hh,
    const float* __restrict__ Wg, const float* __restrict__ a1g, const float* __restrict__ a2g,
    const float* __restrict__ Wn_, const float* __restrict__ a1n, const float* __restrict__ a2n,
    const float* __restrict__ Wd_, const float* __restrict__ a1d, const float* __restrict__ a2d,
    float* __restrict__ WihT, unsigned* __restrict__ wR, unsigned* __restrict__ wZ,
    unsigned* __restrict__ wN, float* __restrict__ rcoef)
{
    int blk = blockIdx.x, tid = threadIdx.x;
    if (blk < 50) {
        int i = blk*256 + tid;
        if (i < 66*192){ int c = i/192, k = i%192; WihT[i] = W_ih[k*66 + c]; }
    } else if (blk < 58) {
        int idx = (blk-50)*256 + tid;                 // < 2048
        int jp = idx >> 6, l = idx & 63;
        wR[idx] = pkf16(W_hh[l*64 + 2*jp],        W_hh[l*64 + 2*jp + 1]);
        wZ[idx] = pkf16(W_hh[(64+l)*64 + 2*jp],   W_hh[(64+l)*64 + 2*jp + 1]);
        wN[idx] = pkf16(W_hh[(128+l)*64 + 2*jp],  W_hh[(128+l)*64 + 2*jp + 1]);
    } else {
        if (tid < 12) {
            int g = tid >> 2, c = tid & 3;
            const float* Wp = g==0 ? Wg  : (g==1 ? Wn_ : Wd_);
            const float* av = (c>>1) ? (g==0 ? a2g : (g==1 ? a2n : a2d))
                                     : (g==0 ? a1g : (g==1 ? a1n : a1d));
            int row = c & 1; float s = 0.f;
            for (int hh = 0; hh < 64; ++hh) s += Wp[row*64 + hh]*av[hh];
            rcoef[g*4 + c] = s;
        }
    }
}

// ---------------------------------------------------------------- pack adj -> bitmasks [3*512][16]u32
__global__ void pack_kernel(const int* __restrict__ Gs, const int* __restrict__ Gn,
                            const int* __restrict__ Gd, unsigned* __restrict__ maskws) {
    int tid = threadIdx.x, lane = tid & 63, w = tid >> 6;
    int gr = blockIdx.x * 4 + w;                    // 0..1535
    int g = gr >> 9, r = gr & 511;
    const int* adj = (g == 0) ? Gs : (g == 1 ? Gn : Gd);
    for (int jw = 0; jw < 8; ++jw) {
        unsigned long long b = __ballot(adj[r * NN + jw * 64 + lane] > 0);
        if (lane == 0) {
            maskws[gr * 16 + jw * 2]     = (unsigned)b;
            maskws[gr * 16 + jw * 2 + 1] = (unsigned)(b >> 32);
        }
    }
}

// ---------------------------------------------------------------- GAT -> U (register tuples + readlane, j-split x2)
#define PW(word, q, lb)                                               \
    _Pragma("unroll")                                                 \
    for (int j2 = 0; j2 < 32; ++j2) {                                 \
        float s2j = rlane(s2r[q], (lb) + j2);                         \
        float x0j = rlane(x0r[q], (lb) + j2);                         \
        float x1j = rlane(x1r[q], (lb) + j2);                         \
        float t = s1 + s2j;                                           \
        t = fmaxf(t, 0.2f * t);                                       \
        float p = __expf(t);                                          \
        p = ((word >> j2) & 1u) ? p : 0.f;                            \
        s += p;                                                       \
        sx0 = fmaf(p, x0j, sx0);                                      \
        sx1 = fmaf(p, x1j, sx1);                                      \
    }

__global__ __launch_bounds__(256) void gat_s_kernel(
    const float* __restrict__ X, const float* __restrict__ rcoef,
    const unsigned* __restrict__ maskws, float* __restrict__ U)
{
    __shared__ float4 part[2][64];
    int tid = threadIdx.x, lane = tid & 63, w = tid >> 6;
    int bid = blockIdx.x;
    int g = bid / 384; int rem = bid % 384; int m = rem >> 2; int rgp = rem & 3;
    int rg = w >> 1, jc = w & 1;

    float4 rc = *(const float4*)&rcoef[g*4];        // (Wa1[0],Wa1[1],Wa2[0],Wa2[1])
    const float* Xm = X + m * (NN*2);

    // register tuples for my 256-j chunk: lane holds j = jc*256 + q*64 + lane
    float s2r[4], x0r[4], x1r[4];
    #pragma unroll
    for (int q = 0; q < 4; ++q) {
        int j = jc*256 + q*64 + lane;
        float2 x = *(const float2*)(Xm + j*2);
        x0r[q] = x.x; x1r[q] = x.y;
        s2r[q] = x.x*rc.z + x.y*rc.w;
    }

    int i = rgp*128 + rg*64 + lane;                 // my row
    float2 xi = *(const float2*)(Xm + i*2);
    float s1 = xi.x*rc.x + xi.y*rc.y;

    const unsigned* mrow = maskws + (g*NN + i)*16 + jc*8;
    uint4 ma = *(const uint4*)mrow;
    uint4 mb = *(const uint4*)(mrow + 4);

    float s = 0.f, sx0 = 0.f, sx1 = 0.f;
    PW(ma.x, 0, 0)  PW(ma.y, 0, 32)
    PW(ma.z, 1, 0)  PW(ma.w, 1, 32)
    PW(mb.x, 2, 0)  PW(mb.y, 2, 32)
    PW(mb.z, 3, 0)  PW(mb.w, 3, 32)

    if (jc == 1) part[rg][lane] = make_float4(s, sx0, sx1, 0.f);
    __syncthreads();
    if (jc == 0) {
        float4 pp = part[rg][lane];
        float inv = 1.f / (s + pp.x);
        *(float2*)&U[((size_t)(g*MM + m)*NN + i)*2] =
            make_float2((sx0 + pp.y)*inv, (sx1 + pp.z)*inv);
    }
}

// ---------------------------------------------------------------- fuse: U -> cat -> spatial -> gx
__global__ __launch_bounds__(256) void fuse_kernel(
    const float* __restrict__ X, const float* __restrict__ U,
    const float* __restrict__ Wg, const float* __restrict__ Wn_, const float* __restrict__ Wd_,
    const float* __restrict__ Wf, const float* __restrict__ bf,
    const float* __restrict__ WihT, const float* __restrict__ b_ih,
    float* __restrict__ gx)
{
    __shared__ __align__(16) float cat[128][68];
    __shared__ __align__(16) float sp[66][68];
    int tid = threadIdx.x, lane = tid & 63, w = tid >> 6;
    int m = blockIdx.x >> 3, n0 = (blockIdx.x & 7) * 64;
    int b = m / TT, t = m % TT;

    for (int idx = tid; idx < 128 * 64; idx += 256) {
        int c = idx >> 6, n = idx & 63;
        int node = m * NN + n0 + n;
        float v;
        if (c < 64) {
            float2 u = *(const float2*)&U[(size_t)node * 2];
            float z = u.x * Wg[c] + u.y * Wg[64 + c];
            v = z > 0.f ? z : expm1f(z);
        } else {
            int cc = c - 64;
            float2 un = *(const float2*)&U[(size_t)(49152 + node) * 2];
            float2 ud = *(const float2*)&U[(size_t)(2 * 49152 + node) * 2];
            float zn = un.x * Wn_[cc] + un.y * Wn_[64 + cc];
            float zd = ud.x * Wd_[cc] + ud.y * Wd_[64 + cc];
            v = (zn > 0.f ? zn : expm1f(zn)) + (zd > 0.f ? zd : expm1f(zd));
        }
        cat[c][n] = v;
    }
    if (lane < 32) {
        int nl = lane >> 1, cc = lane & 1;
        sp[64 + cc][w * 16 + nl] = X[((size_t)m * NN + n0 + w * 16 + nl) * 2 + cc];
    }
    __syncthreads();

    float acc[16];
    float bfl = bf[lane];
    #pragma unroll
    for (int q = 0; q < 16; ++q) acc[q] = bfl;
    #pragma unroll 4
    for (int c = 0; c < 128; ++c) {
        float wf = Wf[c * 64 + lane];
        #pragma unroll
        for (int qq = 0; qq < 4; ++qq) {
            float4 cv = *(const float4*)&cat[c][w * 16 + qq * 4];
            acc[qq * 4 + 0] = fmaf(cv.x, wf, acc[qq * 4 + 0]);
            acc[qq * 4 + 1] = fmaf(cv.y, wf, acc[qq * 4 + 1]);
            acc[qq * 4 + 2] = fmaf(cv.z, wf, acc[qq * 4 + 2]);
            acc[qq * 4 + 3] = fmaf(cv.w, wf, acc[qq * 4 + 3]);
        }
    }
    #pragma unroll
    for (int q = 0; q < 16; ++q) sp[lane][w * 16 + q] = fmaxf(acc[q], 0.f);
    // no barrier: GEMM2 reads only this wave's own sp columns

    float a0[16], a1v[16], a2v[16];
    float b0 = b_ih[lane], b1q = b_ih[64 + lane], b2q = b_ih[128 + lane];
    #pragma unroll
    for (int q = 0; q < 16; ++q) { a0[q] = b0; a1v[q] = b1q; a2v[q] = b2q; }
    #pragma unroll 2
    for (int c = 0; c < 66; ++c) {
        float wv0 = WihT[c * 192 + lane];
        float wv1 = WihT[c * 192 + 64 + lane];
        float wv2 = WihT[c * 192 + 128 + lane];
        #pragma unroll
        for (int qq = 0; qq < 4; ++qq) {
            float4 sv = *(const float4*)&sp[c][w * 16 + qq * 4];
            float sq[4] = {sv.x, sv.y, sv.z, sv.w};
            #pragma unroll
            for (int u = 0; u < 4; ++u) {
                a0[qq * 4 + u]  = fmaf(sq[u], wv0, a0[qq * 4 + u]);
                a1v[qq * 4 + u] = fmaf(sq[u], wv1, a1v[qq * 4 + u]);
                a2v[qq * 4 + u] = fmaf(sq[u], wv2, a2v[qq * 4 + u]);
            }
        }
    }
    #pragma unroll
    for (int q = 0; q < 16; ++q) {
        int n = n0 + w * 16 + q;
        size_t o = ((size_t)(b * NN + n) * TT + t) * 192;
        gx[o + lane]       = a0[q];
        gx[o + 64 + lane]  = a1v[q];
        gx[o + 128 + lane] = a2v[q];
    }
}

// ---------------------------------------------------------------- GRU scan (register f16 weights + dot2) + head
__global__ __launch_bounds__(512) void gru_head_kernel(
    const float* __restrict__ gx,
    const unsigned* __restrict__ wR, const unsigned* __restrict__ wZ,
    const unsigned* __restrict__ wN,
    const float* __restrict__ b_hh,
    const float* __restrict__ W1, const float* __restrict__ b1,
    const float* __restrict__ W2, const float* __restrict__ b2,
    float* __restrict__ out)
{
    __shared__ float hbuf[16][65];
    __shared__ float z1b[16][33];
    int tid = threadIdx.x, lane = tid & 63, wv = tid >> 6;
    int rbase = blockIdx.x * 16 + wv * 2;           // 2 rows per wave

    // weights in registers: lane l holds (W[gate][l][2jp], W[gate][l][2jp+1]) f16-packed
    unsigned wr[32], wz[32], wn[32];
    #pragma unroll
    for (int jp = 0; jp < 32; ++jp) {
        wr[jp] = wR[jp*64 + lane];
        wz[jp] = wZ[jp*64 + lane];
        wn[jp] = wN[jp*64 + lane];
    }

    float bhr = b_hh[lane], bhz = b_hh[64 + lane], bhn = b_hh[128 + lane];
    float h0 = 0.f, h1 = 0.f;
    const float* g0 = gx + (size_t)rbase * TT * 192;

    #pragma unroll 1
    for (int t = 0; t < TT; ++t) {
        const float* p0 = g0 + t * 192;
        const float* p1 = p0 + TT * 192;
        float gxr0 = p0[lane], gxz0 = p0[64 + lane], gxn0 = p0[128 + lane];
        float gxr1 = p1[lane], gxz1 = p1[64 + lane], gxn1 = p1[128 + lane];

        // pack (h[2k],h[2k+1]) f16x2 on even lanes
        float hs0 = __shfl_xor(h0, 1), hs1 = __shfl_xor(h1, 1);
        int hi0 = (int)pkf16(h0, hs0);
        int hi1 = (int)pkf16(h1, hs1);

        float aR0 = bhr, aZ0 = bhz, aN0 = bhn;
        float aR1 = bhr, aZ1 = bhz, aN1 = bhn;
        #pragma unroll
        for (int jp = 0; jp < 32; ++jp) {
            half2v ha = as_h2((unsigned)__builtin_amdgcn_readlane(hi0, 2*jp));
            half2v hb = as_h2((unsigned)__builtin_amdgcn_readlane(hi1, 2*jp));
            aR0 = fdot2(ha, as_h2(wr[jp]), aR0);
            aZ0 = fdot2(ha, as_h2(wz[jp]), aZ0);
            aN0 = fdot2(ha, as_h2(wn[jp]), aN0);
            aR1 = fdot2(hb, as_h2(wr[jp]), aR1);
            aZ1 = fdot2(hb, as_h2(wz[jp]), aZ1);
            aN1 = fdot2(hb, as_h2(wn[jp]), aN1);
        }
        float r0 = 1.f/(1.f + __expf(-(gxr0 + aR0)));
        float z0 = 1.f/(1.f + __expf(-(gxz0 + aZ0)));
        float n0 = 1.f - 2.f/(__expf(2.f*(gxn0 + r0*aN0)) + 1.f);
        h0 = (1.f - z0)*n0 + z0*h0;
        float r1 = 1.f/(1.f + __expf(-(gxr1 + aR1)));
        float z1q = 1.f/(1.f + __expf(-(gxz1 + aZ1)));
        float n1 = 1.f - 2.f/(__expf(2.f*(gxn1 + r1*aN1)) + 1.f);
        h1 = (1.f - z1q)*n1 + z1q*h1;
    }

    hbuf[wv*2][lane] = h0;
    hbuf[wv*2 + 1][lane] = h1;
    __syncthreads();
    {
        int row = tid >> 5, c = tid & 31;           // 16x32 = 512 exact
        float z1 = b1[c];
        #pragma unroll 8
        for (int j = 0; j < 64; ++j) z1 = fmaf(hbuf[row][j], W1[j*32 + c], z1);
        z1b[row][c] = fmaxf(z1, 0.f);
    }
    __syncthreads();
    {
        int row = tid >> 5, p = tid & 31;
        if (p < PP) {
            float o = b2[p];
            #pragma unroll 8
            for (int c = 0; c < 32; ++c) o = fmaf(z1b[row][c], W2[c*PP + p], o);
            int gr = blockIdx.x * 16 + row;
            out[(gr >> 9) * (PP*NN) + p * NN + (gr & 511)] = o;
        }
    }
}

// ---------------------------------------------------------------- launch
extern "C" void kernel_launch(void* const* d_in, const int* in_sizes, int n_in,
                              void* d_out, int out_size, void* d_ws, size_t ws_size,
                              hipStream_t stream) {
    const float* X    = (const float*)d_in[0];
    const int*   Gs   = (const int*)d_in[1];
    const int*   Gn   = (const int*)d_in[2];
    const int*   Gd   = (const int*)d_in[3];
    const float* Wg   = (const float*)d_in[4];
    const float* a1g  = (const float*)d_in[5];
    const float* a2g  = (const float*)d_in[6];
    const float* Wn   = (const float*)d_in[7];
    const float* a1n  = (const float*)d_in[8];
    const float* a2n  = (const float*)d_in[9];
    const float* Wd   = (const float*)d_in[10];
    const float* a1d  = (const float*)d_in[11];
    const float* a2d  = (const float*)d_in[12];
    const float* Wf   = (const float*)d_in[13];
    const float* bf   = (const float*)d_in[14];
    const float* W_ih = (const float*)d_in[15];
    const float* W_hh = (const float*)d_in[16];
    const float* b_ih = (const float*)d_in[17];
    const float* b_hh = (const float*)d_in[18];
    const float* W1   = (const float*)d_in[19];
    const float* b1   = (const float*)d_in[20];
    const float* W2   = (const float*)d_in[21];
    const float* b2   = (const float*)d_in[22];
    float* out = (float*)d_out;

    float* gxw    = (float*)d_ws;                   // [4096][12][192]      9,437,184 f
    float* U      = gxw + 9437184;                  // [3][96][512][2]        294,912 f
    float* WihT   = U + 294912;                     // [66][192]               12,672 f
    float* rcoef  = WihT + 12672;                   // [3][4] (+pad)               16 f
    unsigned* maskws = (unsigned*)(rcoef + 16);     // [1536][16]              24,576 u32
    unsigned* wR  = maskws + 24576;                 // [32][64]                 2,048 u32
    unsigned* wZ  = wR + 2048;
    unsigned* wN  = wZ + 2048;

    prep_kernel<<<59, 256, 0, stream>>>(W_ih, W_hh, Wg, a1g, a2g, Wn, a1n, a2n,
                                        Wd, a1d, a2d, WihT, wR, wZ, wN, rcoef);
    pack_kernel<<<384, 256, 0, stream>>>(Gs, Gn, Gd, maskws);
    gat_s_kernel<<<1152, 256, 0, stream>>>(X, rcoef, maskws, U);
    fuse_kernel<<<768, 256, 0, stream>>>(X, U, Wg, Wn, Wd, Wf, bf, WihT, b_ih, gxw);
    gru_head_kernel<<<256, 512, 0, stream>>>(gxw, wR, wZ, wN, b_hh, W1, b1, W2, b2, out);
}

// Round 11
// 197.750 us; speedup vs baseline: 3.0205x; 1.0227x over previous
//
#include <hip/hip_runtime.h>
#include <hip/hip_bf16.h>

#define BB 8
#define TT 12
#define NN 512
#define HH 64
#define PP 12
#define MM 96

typedef _Float16 half2v __attribute__((ext_vector_type(2)));

__device__ __forceinline__ half2v as_h2(unsigned u){ union{unsigned u; half2v h;} c; c.u=u; return c.h; }
__device__ __forceinline__ unsigned h2_as_u(half2v h){ union{unsigned u; half2v h;} c; c.h=h; return c.u; }
__device__ __forceinline__ float rlane(float v, int l){
    return __int_as_float(__builtin_amdgcn_readlane(__float_as_int(v), l));
}

#if defined(__has_builtin)
#if __has_builtin(__builtin_amdgcn_fdot2)
#define HAVE_FDOT2 1
#endif
#endif
__device__ __forceinline__ float fdot2(half2v a, half2v b, float c){
#ifdef HAVE_FDOT2
    return __builtin_amdgcn_fdot2(a, b, c, false);
#else
    return c + (float)a.x*(float)b.x + (float)a.y*(float)b.y;
#endif
}

__device__ __forceinline__ unsigned pkf16(float a, float b){
    half2v h; h.x = (_Float16)a; h.y = (_Float16)b; return h2_as_u(h);
}

// ---------------------------------------------------------------- setup: pack masks + WihT + f16 W_hh + rcoef (merged)
__global__ void setup_kernel(const int* __restrict__ Gs, const int* __restrict__ Gn,
    const int* __restrict__ Gd,
    const float* __restrict__ W_ih, const float* __restrict__ W_hh,
    const float* __restrict__ Wg, const float* __restrict__ a1g, const float* __restrict__ a2g,
    const float* __restrict__ Wn_, const float* __restrict__ a1n, const float* __restrict__ a2n,
    const float* __restrict__ Wd_, const float* __restrict__ a1d, const float* __restrict__ a2d,
    unsigned* __restrict__ maskws, float* __restrict__ WihT,
    unsigned* __restrict__ wR, unsigned* __restrict__ wZ, unsigned* __restrict__ wN,
    float* __restrict__ rcoef)
{
    int blk = blockIdx.x, tid = threadIdx.x;
    if (blk < 384) {                                  // ---- adj -> bitmasks
        int lane = tid & 63, w = tid >> 6;
        int gr = blk * 4 + w;                         // 0..1535
        int g = gr >> 9, r = gr & 511;
        const int* adj = (g == 0) ? Gs : (g == 1 ? Gn : Gd);
        for (int jw = 0; jw < 8; ++jw) {
            unsigned long long b = __ballot(adj[r * NN + jw * 64 + lane] > 0);
            if (lane == 0) {
                maskws[gr * 16 + jw * 2]     = (unsigned)b;
                maskws[gr * 16 + jw * 2 + 1] = (unsigned)(b >> 32);
            }
        }
    } else if (blk < 434) {                           // ---- WihT transpose
        int i = (blk - 384) * 256 + tid;
        if (i < 66 * 192) { int c = i / 192, k = i % 192; WihT[i] = W_ih[k * 66 + c]; }
    } else if (blk < 442) {                           // ---- f16-pack W_hh (SoA)
        int idx = (blk - 434) * 256 + tid;            // < 2048
        int jp = idx >> 6, l = idx & 63;
        wR[idx] = pkf16(W_hh[l*64 + 2*jp],        W_hh[l*64 + 2*jp + 1]);
        wZ[idx] = pkf16(W_hh[(64+l)*64 + 2*jp],   W_hh[(64+l)*64 + 2*jp + 1]);
        wN[idx] = pkf16(W_hh[(128+l)*64 + 2*jp],  W_hh[(128+l)*64 + 2*jp + 1]);
    } else {                                          // ---- rcoef
        if (tid < 12) {
            int g = tid >> 2, c = tid & 3;
            const float* Wp = g==0 ? Wg  : (g==1 ? Wn_ : Wd_);
            const float* av = (c>>1) ? (g==0 ? a2g : (g==1 ? a2n : a2d))
                                     : (g==0 ? a1g : (g==1 ? a1n : a1d));
            int row = c & 1; float s = 0.f;
            for (int hh = 0; hh < 64; ++hh) s += Wp[row*64 + hh]*av[hh];
            rcoef[g*4 + c] = s;
        }
    }
}

// ---------------------------------------------------------------- GAT -> U (register tuples + readlane, j-split x2)
#define PW(word, q, lb)                                               \
    _Pragma("unroll")                                                 \
    for (int j2 = 0; j2 < 32; ++j2) {                                 \
        float s2j = rlane(s2r[q], (lb) + j2);                         \
        float x0j = rlane(x0r[q], (lb) + j2);                         \
        float x1j = rlane(x1r[q], (lb) + j2);                         \
        float t = s1 + s2j;                                           \
        t = fmaxf(t, 0.2f * t);                                       \
        float p = __expf(t);                                          \
        p = ((word >> j2) & 1u) ? p : 0.f;                            \
        s += p;                                                       \
        sx0 = fmaf(p, x0j, sx0);                                      \
        sx1 = fmaf(p, x1j, sx1);                                      \
    }

__global__ __launch_bounds__(256) void gat_s_kernel(
    const float* __restrict__ X, const float* __restrict__ rcoef,
    const unsigned* __restrict__ maskws, float* __restrict__ U)
{
    __shared__ float4 part[2][64];
    int tid = threadIdx.x, lane = tid & 63, w = tid >> 6;
    int bid = blockIdx.x;
    int g = bid / 384; int rem = bid % 384; int m = rem >> 2; int rgp = rem & 3;
    int rg = w >> 1, jc = w & 1;

    float4 rc = *(const float4*)&rcoef[g*4];        // (Wa1[0],Wa1[1],Wa2[0],Wa2[1])
    const float* Xm = X + m * (NN*2);

    float s2r[4], x0r[4], x1r[4];
    #pragma unroll
    for (int q = 0; q < 4; ++q) {
        int j = jc*256 + q*64 + lane;
        float2 x = *(const float2*)(Xm + j*2);
        x0r[q] = x.x; x1r[q] = x.y;
        s2r[q] = x.x*rc.z + x.y*rc.w;
    }

    int i = rgp*128 + rg*64 + lane;                 // my row
    float2 xi = *(const float2*)(Xm + i*2);
    float s1 = xi.x*rc.x + xi.y*rc.y;

    const unsigned* mrow = maskws + (g*NN + i)*16 + jc*8;
    uint4 ma = *(const uint4*)mrow;
    uint4 mb = *(const uint4*)(mrow + 4);

    float s = 0.f, sx0 = 0.f, sx1 = 0.f;
    PW(ma.x, 0, 0)  PW(ma.y, 0, 32)
    PW(ma.z, 1, 0)  PW(ma.w, 1, 32)
    PW(mb.x, 2, 0)  PW(mb.y, 2, 32)
    PW(mb.z, 3, 0)  PW(mb.w, 3, 32)

    if (jc == 1) part[rg][lane] = make_float4(s, sx0, sx1, 0.f);
    __syncthreads();
    if (jc == 0) {
        float4 pp = part[rg][lane];
        float inv = 1.f / (s + pp.x);
        *(float2*)&U[((size_t)(g*MM + m)*NN + i)*2] =
            make_float2((sx0 + pp.y)*inv, (sx1 + pp.z)*inv);
    }
}

// ---------------------------------------------------------------- fuse v2: reg-staged U, fast elu, aliased LDS
__global__ __launch_bounds__(256) void fuse_kernel(
    const float* __restrict__ X, const float* __restrict__ U,
    const float* __restrict__ Wg, const float* __restrict__ Wn_, const float* __restrict__ Wd_,
    const float* __restrict__ Wf, const float* __restrict__ bf,
    const float* __restrict__ WihT, const float* __restrict__ b_ih,
    float* __restrict__ gx)
{
    __shared__ __align__(16) float buf[128][68];    // 34.8 KB: cat, then sp aliased in rows 0..65
    int tid = threadIdx.x, lane = tid & 63, w = tid >> 6;
    int m = blockIdx.x >> 3, n0 = (blockIdx.x & 7) * 64;
    int b = m / TT, t = m % TT;

    // ---- staging: node-per-lane, U in registers, 32 c-rows per thread
    {
        int n = tid & 63, cq = tid >> 6;
        int node = m * NN + n0 + n;
        if (cq < 2) {
            float2 u = *(const float2*)&U[(size_t)node * 2];
            int c0 = cq * 32;
            #pragma unroll
            for (int cc = 0; cc < 32; ++cc) {
                int c = c0 + cc;
                float z = u.x * Wg[c] + u.y * Wg[64 + c];
                buf[c][n] = z > 0.f ? z : __expf(z) - 1.f;
            }
        } else {
            float2 un = *(const float2*)&U[(size_t)(49152 + node) * 2];
            float2 ud = *(const float2*)&U[(size_t)(2 * 49152 + node) * 2];
            int c0 = (cq - 2) * 32;
            #pragma unroll
            for (int cc = 0; cc < 32; ++cc) {
                int c = c0 + cc;
                float zn = un.x * Wn_[c] + un.y * Wn_[64 + c];
                float zd = ud.x * Wd_[c] + ud.y * Wd_[64 + c];
                float vn = zn > 0.f ? zn : __expf(zn) - 1.f;
                float vd = zd > 0.f ? zd : __expf(zd) - 1.f;
                buf[64 + c][n] = vn + vd;
            }
        }
    }
    __syncthreads();

    // ---- GEMM1: spatial[h=lane][n=w*16+q] = relu(bf + sum_c buf[c][n]*Wf[c][h])
    float acc[16];
    float bfl = bf[lane];
    #pragma unroll
    for (int q = 0; q < 16; ++q) acc[q] = bfl;
    #pragma unroll 4
    for (int c = 0; c < 128; ++c) {
        float wf = Wf[c * 64 + lane];
        #pragma unroll
        for (int qq = 0; qq < 4; ++qq) {
            float4 cv = *(const float4*)&buf[c][w * 16 + qq * 4];
            acc[qq * 4 + 0] = fmaf(cv.x, wf, acc[qq * 4 + 0]);
            acc[qq * 4 + 1] = fmaf(cv.y, wf, acc[qq * 4 + 1]);
            acc[qq * 4 + 2] = fmaf(cv.z, wf, acc[qq * 4 + 2]);
            acc[qq * 4 + 3] = fmaf(cv.w, wf, acc[qq * 4 + 3]);
        }
    }
    // sp aliases buf rows 0..65, my own columns only; ds ops are in-order per wave,
    // and no other wave ever touches my 16 columns -> no barrier needed.
    #pragma unroll
    for (int q = 0; q < 16; ++q) buf[lane][w * 16 + q] = fmaxf(acc[q], 0.f);
    if (lane < 32) {
        int nl = lane >> 1, cc = lane & 1;
        buf[64 + cc][w * 16 + nl] = X[((size_t)m * NN + n0 + w * 16 + nl) * 2 + cc];
    }

    // ---- GEMM2: gx[k][n] = b_ih + sum_{c<66} buf[c][n]*WihT[c][k], k = lane+{0,64,128}
    float a0[16], a1v[16], a2v[16];
    float b0 = b_ih[lane], b1q = b_ih[64 + lane], b2q = b_ih[128 + lane];
    #pragma unroll
    for (int q = 0; q < 16; ++q) { a0[q] = b0; a1v[q] = b1q; a2v[q] = b2q; }
    #pragma unroll 2
    for (int c = 0; c < 66; ++c) {
        float wv0 = WihT[c * 192 + lane];
        float wv1 = WihT[c * 192 + 64 + lane];
        float wv2 = WihT[c * 192 + 128 + lane];
        #pragma unroll
        for (int qq = 0; qq < 4; ++qq) {
            float4 sv = *(const float4*)&buf[c][w * 16 + qq * 4];
            float sq[4] = {sv.x, sv.y, sv.z, sv.w};
            #pragma unroll
            for (int u = 0; u < 4; ++u) {
                a0[qq * 4 + u]  = fmaf(sq[u], wv0, a0[qq * 4 + u]);
                a1v[qq * 4 + u] = fmaf(sq[u], wv1, a1v[qq * 4 + u]);
                a2v[qq * 4 + u] = fmaf(sq[u], wv2, a2v[qq * 4 + u]);
            }
        }
    }
    #pragma unroll
    for (int q = 0; q < 16; ++q) {
        int n = n0 + w * 16 + q;
        size_t o = ((size_t)(b * NN + n) * TT + t) * 192;
        gx[o + lane]       = a0[q];
        gx[o + 64 + lane]  = a1v[q];
        gx[o + 128 + lane] = a2v[q];
    }
}

// ---------------------------------------------------------------- GRU scan (register f16 weights + dot2) + head
__global__ __launch_bounds__(512) void gru_head_kernel(
    const float* __restrict__ gx,
    const unsigned* __restrict__ wR, const unsigned* __restrict__ wZ,
    const unsigned* __restrict__ wN,
    const float* __restrict__ b_hh,
    const float* __restrict__ W1, const float* __restrict__ b1,
    const float* __restrict__ W2, const float* __restrict__ b2,
    float* __restrict__ out)
{
    __shared__ float hbuf[16][65];
    __shared__ float z1b[16][33];
    int tid = threadIdx.x, lane = tid & 63, wv = tid >> 6;
    int rbase = blockIdx.x * 16 + wv * 2;           // 2 rows per wave

    unsigned wr[32], wz[32], wn[32];
    #pragma unroll
    for (int jp = 0; jp < 32; ++jp) {
        wr[jp] = wR[jp*64 + lane];
        wz[jp] = wZ[jp*64 + lane];
        wn[jp] = wN[jp*64 + lane];
    }

    float bhr = b_hh[lane], bhz = b_hh[64 + lane], bhn = b_hh[128 + lane];
    float h0 = 0.f, h1 = 0.f;
    const float* g0 = gx + (size_t)rbase * TT * 192;

    #pragma unroll 1
    for (int t = 0; t < TT; ++t) {
        const float* p0 = g0 + t * 192;
        const float* p1 = p0 + TT * 192;
        float gxr0 = p0[lane], gxz0 = p0[64 + lane], gxn0 = p0[128 + lane];
        float gxr1 = p1[lane], gxz1 = p1[64 + lane], gxn1 = p1[128 + lane];

        float hs0 = __shfl_xor(h0, 1), hs1 = __shfl_xor(h1, 1);
        int hi0 = (int)pkf16(h0, hs0);
        int hi1 = (int)pkf16(h1, hs1);

        float aR0 = bhr, aZ0 = bhz, aN0 = bhn;
        float aR1 = bhr, aZ1 = bhz, aN1 = bhn;
        #pragma unroll
        for (int jp = 0; jp < 32; ++jp) {
            half2v ha = as_h2((unsigned)__builtin_amdgcn_readlane(hi0, 2*jp));
            half2v hb = as_h2((unsigned)__builtin_amdgcn_readlane(hi1, 2*jp));
            aR0 = fdot2(ha, as_h2(wr[jp]), aR0);
            aZ0 = fdot2(ha, as_h2(wz[jp]), aZ0);
            aN0 = fdot2(ha, as_h2(wn[jp]), aN0);
            aR1 = fdot2(hb, as_h2(wr[jp]), aR1);
            aZ1 = fdot2(hb, as_h2(wz[jp]), aZ1);
            aN1 = fdot2(hb, as_h2(wn[jp]), aN1);
        }
        float r0 = 1.f/(1.f + __expf(-(gxr0 + aR0)));
        float z0 = 1.f/(1.f + __expf(-(gxz0 + aZ0)));
        float n0 = 1.f - 2.f/(__expf(2.f*(gxn0 + r0*aN0)) + 1.f);
        h0 = (1.f - z0)*n0 + z0*h0;
        float r1 = 1.f/(1.f + __expf(-(gxr1 + aR1)));
        float z1q = 1.f/(1.f + __expf(-(gxz1 + aZ1)));
        float n1 = 1.f - 2.f/(__expf(2.f*(gxn1 + r1*aN1)) + 1.f);
        h1 = (1.f - z1q)*n1 + z1q*h1;
    }

    hbuf[wv*2][lane] = h0;
    hbuf[wv*2 + 1][lane] = h1;
    __syncthreads();
    {
        int row = tid >> 5, c = tid & 31;           // 16x32 = 512 exact
        float z1 = b1[c];
        #pragma unroll 8
        for (int j = 0; j < 64; ++j) z1 = fmaf(hbuf[row][j], W1[j*32 + c], z1);
        z1b[row][c] = fmaxf(z1, 0.f);
    }
    __syncthreads();
    {
        int row = tid >> 5, p = tid & 31;
        if (p < PP) {
            float o = b2[p];
            #pragma unroll 8
            for (int c = 0; c < 32; ++c) o = fmaf(z1b[row][c], W2[c*PP + p], o);
            int gr = blockIdx.x * 16 + row;
            out[(gr >> 9) * (PP*NN) + p * NN + (gr & 511)] = o;
        }
    }
}

// ---------------------------------------------------------------- launch
extern "C" void kernel_launch(void* const* d_in, const int* in_sizes, int n_in,
                              void* d_out, int out_size, void* d_ws, size_t ws_size,
                              hipStream_t stream) {
    const float* X    = (const float*)d_in[0];
    const int*   Gs   = (const int*)d_in[1];
    const int*   Gn   = (const int*)d_in[2];
    const int*   Gd   = (const int*)d_in[3];
    const float* Wg   = (const float*)d_in[4];
    const float* a1g  = (const float*)d_in[5];
    const float* a2g  = (const float*)d_in[6];
    const float* Wn   = (const float*)d_in[7];
    const float* a1n  = (const float*)d_in[8];
    const float* a2n  = (const float*)d_in[9];
    const float* Wd   = (const float*)d_in[10];
    const float* a1d  = (const float*)d_in[11];
    const float* a2d  = (const float*)d_in[12];
    const float* Wf   = (const float*)d_in[13];
    const float* bf   = (const float*)d_in[14];
    const float* W_ih = (const float*)d_in[15];
    const float* W_hh = (const float*)d_in[16];
    const float* b_ih = (const float*)d_in[17];
    const float* b_hh = (const float*)d_in[18];
    const float* W1   = (const float*)d_in[19];
    const float* b1   = (const float*)d_in[20];
    const float* W2   = (const float*)d_in[21];
    const float* b2   = (const float*)d_in[22];
    float* out = (float*)d_out;

    float* gxw    = (float*)d_ws;                   // [4096][12][192]      9,437,184 f
    float* U      = gxw + 9437184;                  // [3][96][512][2]        294,912 f
    float* WihT   = U + 294912;                     // [66][192]               12,672 f
    float* rcoef  = WihT + 12672;                   // [3][4] (+pad)               16 f
    unsigned* maskws = (unsigned*)(rcoef + 16);     // [1536][16]              24,576 u32
    unsigned* wR  = maskws + 24576;                 // [32][64]                 2,048 u32
    unsigned* wZ  = wR + 2048;
    unsigned* wN  = wZ + 2048;

    setup_kernel<<<443, 256, 0, stream>>>(Gs, Gn, Gd, W_ih, W_hh, Wg, a1g, a2g,
                                          Wn, a1n, a2n, Wd, a1d, a2d,
                                          maskws, WihT, wR, wZ, wN, rcoef);
    gat_s_kernel<<<1152, 256, 0, stream>>>(X, rcoef, maskws, U);
    fuse_kernel<<<768, 256, 0, stream>>>(X, U, Wg, Wn, Wd, Wf, bf, WihT, b_ih, gxw);
    gru_head_kernel<<<256, 512, 0, stream>>>(gxw, wR, wZ, wN, b_hh, W1, b1, W2, b2, out);
}